// Round 2
// baseline (376.160 us; speedup 1.0000x reference)
//
#include <hip/hip_runtime.h>
#include <stdint.h>

#define DIM 33
#define D2 (DIM * DIM)          // 1089
#define NENT (DIM * DIM * DIM)  // 35937
#define HW 2073600              // 1920*1080
#define NIMG 8
#define HW4 (HW / 4)            // 518400 quad-pixels per image-channel-plane
#define QP (NIMG * HW4)         // 4147200 total quad-pixels
#define BLK 1024
#define NBLK 256                // one persistent block per CU (LDS-capped anyway)
#define STRIDE (BLK * NBLK)     // 262144
#define STRIDE2 (2 * STRIDE)    // 524288

typedef float f32x4 __attribute__((ext_vector_type(4)));
typedef uint32_t u32x4 __attribute__((ext_vector_type(4)));

__device__ __forceinline__ float lerpf(float a, float b, float t) {
    return fmaf(t, b - a, a);
}

// 10-10-10 fixed point pack: T[e] = qr | qg<<10 | qb<<20, e=(b*33+g)*33+r
__global__ __launch_bounds__(256) void build_packed10(const float* __restrict__ lut,
                                                      uint32_t* __restrict__ T) {
    int e = blockIdx.x * 256 + threadIdx.x;
    if (e >= NENT) return;
    uint32_t q0 = (uint32_t)(lut[e] * 1023.f + 0.5f);
    uint32_t q1 = (uint32_t)(lut[NENT + e] * 1023.f + 0.5f);
    uint32_t q2 = (uint32_t)(lut[2 * NENT + e] * 1023.f + 0.5f);
    T[e] = q0 | (q1 << 10) | (q2 << 20);
}

#define U0(v) ((float)((v) & 1023u))
#define U1(v) ((float)(((v) >> 10) & 1023u))
#define U2(v) ((float)((v) >> 20))

__device__ __forceinline__ void loadq(const float* __restrict__ x, int j, bool valid,
                                      f32x4& R, f32x4& G, f32x4& B) {
    if (valid) {
        int img = j / HW4;
        int i = (j - img * HW4) * 4;
        const float* xp = x + (size_t)img * 3 * HW + i;
        R = *(const f32x4*)xp;
        G = *(const f32x4*)(xp + HW);
        B = *(const f32x4*)(xp + 2 * HW);
    } else {
        R = f32x4{0.f, 0.f, 0.f, 0.f};
        G = f32x4{0.f, 0.f, 0.f, 0.f};
        B = f32x4{0.f, 0.f, 0.f, 0.f};
    }
}

__device__ __forceinline__ void idxfrac(float r, float g, float b,
                                        int& base, float& rd, float& gd, float& bd) {
    const float inv = 32.0f / 1.000001f;  // keep EXACT expression from verified kernel
    float xr = r * inv;
    float xg = g * inv;
    float xb = b * inv;
    // x >= 0, so trunc == floor; only upper clamp needed
    int ri = (int)xr; ri = ri > DIM - 2 ? DIM - 2 : ri;
    int gi = (int)xg; gi = gi > DIM - 2 ? DIM - 2 : gi;
    int bi = (int)xb; bi = bi > DIM - 2 ? DIM - 2 : bi;
    rd = xr - (float)ri;
    gd = xg - (float)gi;
    bd = xb - (float)bi;
    base = (bi * DIM + gi) * DIM + ri;
}

__device__ __forceinline__ void interp(const uint32_t (&v)[8], float rd, float gd, float bd,
                                       float& o0, float& o1, float& o2) {
    const float qs = 1.0f / 1023.0f;
    {   // channel 0
        float q00 = lerpf(U0(v[0]), U0(v[1]), rd);
        float q01 = lerpf(U0(v[2]), U0(v[3]), rd);
        float q10 = lerpf(U0(v[4]), U0(v[5]), rd);
        float q11 = lerpf(U0(v[6]), U0(v[7]), rd);
        o0 = lerpf(lerpf(q00, q01, gd), lerpf(q10, q11, gd), bd) * qs;
    }
    {   // channel 1
        float q00 = lerpf(U1(v[0]), U1(v[1]), rd);
        float q01 = lerpf(U1(v[2]), U1(v[3]), rd);
        float q10 = lerpf(U1(v[4]), U1(v[5]), rd);
        float q11 = lerpf(U1(v[6]), U1(v[7]), rd);
        o1 = lerpf(lerpf(q00, q01, gd), lerpf(q10, q11, gd), bd) * qs;
    }
    {   // channel 2
        float q00 = lerpf(U2(v[0]), U2(v[1]), rd);
        float q01 = lerpf(U2(v[2]), U2(v[3]), rd);
        float q10 = lerpf(U2(v[4]), U2(v[5]), rd);
        float q11 = lerpf(U2(v[6]), U2(v[7]), rd);
        o2 = lerpf(lerpf(q00, q01, gd), lerpf(q10, q11, gd), bd) * qs;
    }
}

__global__ __launch_bounds__(1024) void lut3d_lds(const float* __restrict__ x,
                                                  const uint32_t* __restrict__ T,
                                                  float* __restrict__ out) {
    __shared__ __align__(16) uint32_t L[NENT];  // 143,748 B of the 160 KiB LDS

    // Vectorized table fill: 8984 u32x4 + 1 tail word.
    {
        const u32x4* T4 = (const u32x4*)T;
        u32x4* L4 = (u32x4*)L;
        for (int e = threadIdx.x; e < NENT / 4; e += BLK) L4[e] = T4[e];
        if (threadIdx.x == 0) L[NENT - 1] = T[NENT - 1];
    }

    const int j0 = blockIdx.x * BLK + threadIdx.x;

    // First pair's x loads issued BEFORE the barrier: latency hides under table fill.
    f32x4 RA, GA, BA, RB, GB, BB;
    loadq(x, j0, true, RA, GA, BA);
    loadq(x, j0 + STRIDE, true, RB, GB, BB);  // j0+STRIDE <= 524287 < QP always

    __syncthreads();

    // 16 quads per lane max: pairs p=0..7. Quads 0..14 always in-bounds;
    // only quad 15 (pair 7, B-slot) needs a guard.
#pragma unroll 1
    for (int p = 0; p < 8; ++p) {
        const int jA = j0 + p * STRIDE2;
        const int jB = jA + STRIDE;
        const bool vB = (jB < QP);

        // Phase 1: all 8 pixels' indices + fracs (RA..BB die here).
        int base[8];
        float rd[8], gd[8], bd[8];
#pragma unroll
        for (int k = 0; k < 4; ++k)
            idxfrac(RA[k], GA[k], BA[k], base[k], rd[k], gd[k], bd[k]);
#pragma unroll
        for (int k = 0; k < 4; ++k)
            idxfrac(RB[k], GB[k], BB[k], base[4 + k], rd[4 + k], gd[4 + k], bd[4 + k]);

        // Phase 2: batch-issue all 64 LDS gathers (32x ds_read2_b32).
        uint32_t v[8][8];
#pragma unroll
        for (int k = 0; k < 8; ++k) {
            const int b0 = base[k];
            v[k][0] = L[b0];            v[k][1] = L[b0 + 1];
            v[k][2] = L[b0 + DIM];      v[k][3] = L[b0 + DIM + 1];
            v[k][4] = L[b0 + D2];       v[k][5] = L[b0 + D2 + 1];
            v[k][6] = L[b0 + D2 + DIM]; v[k][7] = L[b0 + D2 + DIM + 1];
        }

        // Phase 3: prefetch next pair's x while gathers are in flight.
        if (p < 7) {
            const int jA2 = jA + STRIDE2;  // <= j0+14*STRIDE < QP always
            loadq(x, jA2, true, RA, GA, BA);
            loadq(x, jA2 + STRIDE, jA2 + STRIDE < QP, RB, GB, BB);
        }

        // Phase 4: consume (compiler stages lgkmcnt per pixel), then store.
        float o[8][3];
#pragma unroll
        for (int k = 0; k < 8; ++k)
            interp(v[k], rd[k], gd[k], bd[k], o[k][0], o[k][1], o[k][2]);

        {
            const int img = jA / HW4;
            const int i = (jA - img * HW4) * 4;
            float* op = out + (size_t)img * 3 * HW + i;
            f32x4 v0 = {o[0][0], o[1][0], o[2][0], o[3][0]};
            f32x4 v1 = {o[0][1], o[1][1], o[2][1], o[3][1]};
            f32x4 v2 = {o[0][2], o[1][2], o[2][2], o[3][2]};
            __builtin_nontemporal_store(v0, (f32x4*)op);
            __builtin_nontemporal_store(v1, (f32x4*)(op + HW));
            __builtin_nontemporal_store(v2, (f32x4*)(op + 2 * HW));
        }
        if (vB) {
            const int img = jB / HW4;
            const int i = (jB - img * HW4) * 4;
            float* op = out + (size_t)img * 3 * HW + i;
            f32x4 v0 = {o[4][0], o[5][0], o[6][0], o[7][0]};
            f32x4 v1 = {o[4][1], o[5][1], o[6][1], o[7][1]};
            f32x4 v2 = {o[4][2], o[5][2], o[6][2], o[7][2]};
            __builtin_nontemporal_store(v0, (f32x4*)op);
            __builtin_nontemporal_store(v1, (f32x4*)(op + HW));
            __builtin_nontemporal_store(v2, (f32x4*)(op + 2 * HW));
        }
    }
}

// Fallback if workspace is too small: direct fp32 gathers from global LUT.
__global__ __launch_bounds__(256) void lut3d_direct(const float* __restrict__ x,
                                                    const float* __restrict__ lut,
                                                    float* __restrict__ out) {
    const int img = blockIdx.y;
    const int i = (blockIdx.x * 256 + threadIdx.x) * 4;
    const float* xp = x + (size_t)img * 3 * HW + i;
    f32x4 Rv = *(const f32x4*)xp;
    f32x4 Gv = *(const f32x4*)(xp + HW);
    f32x4 Bv = *(const f32x4*)(xp + 2 * HW);
    float o0[4], o1[4], o2[4];
    const float inv = 32.0f / 1.000001f;
#pragma unroll
    for (int k = 0; k < 4; ++k) {
        float xr = Rv[k] * inv;
        float xg = Gv[k] * inv;
        float xb = Bv[k] * inv;
        int ri = (int)xr; ri = ri < 0 ? 0 : (ri > DIM - 2 ? DIM - 2 : ri);
        int gi = (int)xg; gi = gi < 0 ? 0 : (gi > DIM - 2 ? DIM - 2 : gi);
        int bi = (int)xb; bi = bi < 0 ? 0 : (bi > DIM - 2 ? DIM - 2 : bi);
        float rd = xr - (float)ri;
        float gd = xg - (float)gi;
        float bd = xb - (float)bi;
        int base = (bi * DIM + gi) * DIM + ri;
        float oc[3];
#pragma unroll
        for (int c = 0; c < 3; ++c) {
            const float* Lp = lut + c * NENT + base;
            float v000 = Lp[0],        v001 = Lp[1];
            float v010 = Lp[DIM],      v011 = Lp[DIM + 1];
            float v100 = Lp[D2],       v101 = Lp[D2 + 1];
            float v110 = Lp[D2 + DIM], v111 = Lp[D2 + DIM + 1];
            float q0 = lerpf(v000, v001, rd);
            float q1 = lerpf(v010, v011, rd);
            float q2 = lerpf(v100, v101, rd);
            float q3 = lerpf(v110, v111, rd);
            float p0 = lerpf(q0, q1, gd);
            float p1 = lerpf(q2, q3, gd);
            oc[c] = lerpf(p0, p1, bd);
        }
        o0[k] = oc[0]; o1[k] = oc[1]; o2[k] = oc[2];
    }
    float* op = out + (size_t)img * 3 * HW + i;
    f32x4 v0 = {o0[0], o0[1], o0[2], o0[3]};
    f32x4 v1 = {o1[0], o1[1], o1[2], o1[3]};
    f32x4 v2 = {o2[0], o2[1], o2[2], o2[3]};
    *(f32x4*)op = v0;
    *(f32x4*)(op + HW) = v1;
    *(f32x4*)(op + 2 * HW) = v2;
}

extern "C" void kernel_launch(void* const* d_in, const int* in_sizes, int n_in,
                              void* d_out, int out_size, void* d_ws, size_t ws_size,
                              hipStream_t stream) {
    const float* lut = (const float*)d_in[0];
    const float* x   = (const float*)d_in[1];
    float* out = (float*)d_out;

    if (ws_size >= (size_t)NENT * 4) {
        uint32_t* T = (uint32_t*)d_ws;
        build_packed10<<<(NENT + 255) / 256, 256, 0, stream>>>(lut, T);
        lut3d_lds<<<NBLK, BLK, 0, stream>>>(x, T, out);
    } else {
        const dim3 grid(HW / 4 / 256, NIMG);
        lut3d_direct<<<grid, dim3(256), 0, stream>>>(x, lut, out);
    }
}

// Round 3
// 375.843 us; speedup vs baseline: 1.0008x; 1.0008x over previous
//
#include <hip/hip_runtime.h>
#include <stdint.h>

#define DIM 33
#define D2 (DIM * DIM)          // 1089
#define NENT (DIM * DIM * DIM)  // 35937
#define HW 2073600              // 1920*1080
#define NIMG 8
#define HW4 (HW / 4)            // 518400 quad-pixels per image-channel-plane
#define QP (NIMG * HW4)         // 4147200 total quad-pixels
#define BLK 1024
#define NBLK 256                // one persistent block per CU (LDS-capped anyway)
#define STRIDE (BLK * NBLK)     // 262144
#define STRIDE2 (2 * STRIDE)    // 524288

typedef float f32x4 __attribute__((ext_vector_type(4)));
typedef uint32_t u32x4 __attribute__((ext_vector_type(4)));

__device__ __forceinline__ float lerpf(float a, float b, float t) {
    return fmaf(t, b - a, a);
}

// 10-10-10 fixed point pack: T[e] = qr | qg<<10 | qb<<20, e=(b*33+g)*33+r
__global__ __launch_bounds__(256) void build_packed10(const float* __restrict__ lut,
                                                      uint32_t* __restrict__ T) {
    int e = blockIdx.x * 256 + threadIdx.x;
    if (e >= NENT) return;
    uint32_t q0 = (uint32_t)(lut[e] * 1023.f + 0.5f);
    uint32_t q1 = (uint32_t)(lut[NENT + e] * 1023.f + 0.5f);
    uint32_t q2 = (uint32_t)(lut[2 * NENT + e] * 1023.f + 0.5f);
    T[e] = q0 | (q1 << 10) | (q2 << 20);
}

#define U0(v) ((float)((v) & 1023u))
#define U1(v) ((float)(((v) >> 10) & 1023u))
#define U2(v) ((float)((v) >> 20))

__device__ __forceinline__ void loadq(const float* __restrict__ x, int j, bool valid,
                                      f32x4& R, f32x4& G, f32x4& B) {
    if (valid) {
        int img = j / HW4;
        int i = (j - img * HW4) * 4;
        const float* xp = x + (size_t)img * 3 * HW + i;
        R = *(const f32x4*)xp;
        G = *(const f32x4*)(xp + HW);
        B = *(const f32x4*)(xp + 2 * HW);
    } else {
        R = f32x4{0.f, 0.f, 0.f, 0.f};
        G = f32x4{0.f, 0.f, 0.f, 0.f};
        B = f32x4{0.f, 0.f, 0.f, 0.f};
    }
}

__device__ __forceinline__ void idxfrac(float r, float g, float b,
                                        int& base, float& rd, float& gd, float& bd) {
    const float inv = 32.0f / 1.000001f;  // keep EXACT expression from verified kernel
    float xr = r * inv;
    float xg = g * inv;
    float xb = b * inv;
    // x >= 0, so trunc == floor; only upper clamp needed
    int ri = (int)xr; ri = ri > DIM - 2 ? DIM - 2 : ri;
    int gi = (int)xg; gi = gi > DIM - 2 ? DIM - 2 : gi;
    int bi = (int)xb; bi = bi > DIM - 2 ? DIM - 2 : bi;
    rd = xr - (float)ri;
    gd = xg - (float)gi;
    bd = xb - (float)bi;
    base = (bi * DIM + gi) * DIM + ri;
}

__device__ __forceinline__ void gather8(const uint32_t* __restrict__ L, int b0,
                                        uint32_t (&v)[8]) {
    v[0] = L[b0];            v[1] = L[b0 + 1];
    v[2] = L[b0 + DIM];      v[3] = L[b0 + DIM + 1];
    v[4] = L[b0 + D2];       v[5] = L[b0 + D2 + 1];
    v[6] = L[b0 + D2 + DIM]; v[7] = L[b0 + D2 + DIM + 1];
}

// Channel-outer interp + store for one quad: only 4 output regs live at a time.
__device__ __forceinline__ void interp_store(float* __restrict__ out, int j,
                                             const uint32_t (&v)[4][8],
                                             const float (&rd)[4],
                                             const float (&gd)[4],
                                             const float (&bd)[4]) {
    const float qs = 1.0f / 1023.0f;
    const int img = j / HW4;
    const int i = (j - img * HW4) * 4;
    float* op = out + (size_t)img * 3 * HW + i;
    {   // channel 0
        f32x4 o;
#pragma unroll
        for (int k = 0; k < 4; ++k) {
            float q00 = lerpf(U0(v[k][0]), U0(v[k][1]), rd[k]);
            float q01 = lerpf(U0(v[k][2]), U0(v[k][3]), rd[k]);
            float q10 = lerpf(U0(v[k][4]), U0(v[k][5]), rd[k]);
            float q11 = lerpf(U0(v[k][6]), U0(v[k][7]), rd[k]);
            o[k] = lerpf(lerpf(q00, q01, gd[k]), lerpf(q10, q11, gd[k]), bd[k]) * qs;
        }
        __builtin_nontemporal_store(o, (f32x4*)op);
    }
    {   // channel 1
        f32x4 o;
#pragma unroll
        for (int k = 0; k < 4; ++k) {
            float q00 = lerpf(U1(v[k][0]), U1(v[k][1]), rd[k]);
            float q01 = lerpf(U1(v[k][2]), U1(v[k][3]), rd[k]);
            float q10 = lerpf(U1(v[k][4]), U1(v[k][5]), rd[k]);
            float q11 = lerpf(U1(v[k][6]), U1(v[k][7]), rd[k]);
            o[k] = lerpf(lerpf(q00, q01, gd[k]), lerpf(q10, q11, gd[k]), bd[k]) * qs;
        }
        __builtin_nontemporal_store(o, (f32x4*)(op + HW));
    }
    {   // channel 2
        f32x4 o;
#pragma unroll
        for (int k = 0; k < 4; ++k) {
            float q00 = lerpf(U2(v[k][0]), U2(v[k][1]), rd[k]);
            float q01 = lerpf(U2(v[k][2]), U2(v[k][3]), rd[k]);
            float q10 = lerpf(U2(v[k][4]), U2(v[k][5]), rd[k]);
            float q11 = lerpf(U2(v[k][6]), U2(v[k][7]), rd[k]);
            o[k] = lerpf(lerpf(q00, q01, gd[k]), lerpf(q10, q11, gd[k]), bd[k]) * qs;
        }
        __builtin_nontemporal_store(o, (f32x4*)(op + 2 * HW));
    }
}

// __launch_bounds__(1024, 4): 1024-thread block = 4 waves/EU min occupancy,
// which raises the compiler's VGPR cap to 128 (round-1's implicit cap of 64
// caused spills -> +180MB scratch HBM traffic).
__global__ __launch_bounds__(1024, 4) void lut3d_lds(const float* __restrict__ x,
                                                     const uint32_t* __restrict__ T,
                                                     float* __restrict__ out) {
    __shared__ __align__(16) uint32_t L[NENT];  // 143,748 B of the 160 KiB LDS

    // Vectorized table fill: 8984 u32x4 + 1 tail word.
    {
        const u32x4* T4 = (const u32x4*)T;
        u32x4* L4 = (u32x4*)L;
        for (int e = threadIdx.x; e < NENT / 4; e += BLK) L4[e] = T4[e];
        if (threadIdx.x == 0) L[NENT - 1] = T[NENT - 1];
    }

    const int j0 = blockIdx.x * BLK + threadIdx.x;

    // Quads 0 and 1 loaded BEFORE the barrier: latency hides under table fill.
    f32x4 RA, GA, BA, RB, GB, BB;
    loadq(x, j0, true, RA, GA, BA);            // quad 0
    loadq(x, j0 + STRIDE, true, RB, GB, BB);   // quad 1 (always < QP)

    __syncthreads();

    // Prologue of the 2-stage pipeline: quad 0's fracs + gathers in flight.
    uint32_t vA[4][8], vB[4][8];
    float rdA[4], gdA[4], bdA[4], rdB[4], gdB[4], bdB[4];
    {
        int baseA[4];
#pragma unroll
        for (int k = 0; k < 4; ++k)
            idxfrac(RA[k], GA[k], BA[k], baseA[k], rdA[k], gdA[k], bdA[k]);
#pragma unroll
        for (int k = 0; k < 4; ++k) gather8(L, baseA[k], vA[k]);
    }

    // 16 quads per lane: pairs p=0..7. Quads 0..14 always in-bounds;
    // only quad 15 (pair 7, B-slot) needs load/store guards.
#pragma unroll 1
    for (int p = 0; p < 8; ++p) {
        const int jA = j0 + p * STRIDE2;
        const int jB = jA + STRIDE;

        // Phase 1: quad (2p+1) fracs + issue its 32 LDS gathers.
        {
            int baseB[4];
#pragma unroll
            for (int k = 0; k < 4; ++k)
                idxfrac(RB[k], GB[k], BB[k], baseB[k], rdB[k], gdB[k], bdB[k]);
#pragma unroll
            for (int k = 0; k < 4; ++k) gather8(L, baseB[k], vB[k]);
        }

        // Phase 2: prefetch next pair's inputs (quads 2p+2, 2p+3).
        f32x4 RA2, GA2, BA2, RB2, GB2, BB2;
        const bool pv = (p < 7);
        loadq(x, jA + STRIDE2, pv, RA2, GA2, BA2);
        loadq(x, jB + STRIDE2, pv && (jB + STRIDE2 < QP), RB2, GB2, BB2);

        // Phase 3: consume quad 2p (vA complete; vB still in flight).
        interp_store(out, jA, vA, rdA, gdA, bdA);

        // Phase 4: quad (2p+2) fracs + issue its gathers (overwrites vA).
        // At p==7 this runs on zeros (base 0) -> harmless dead LDS reads.
        {
            int baseA[4];
#pragma unroll
            for (int k = 0; k < 4; ++k)
                idxfrac(RA2[k], GA2[k], BA2[k], baseA[k], rdA[k], gdA[k], bdA[k]);
#pragma unroll
            for (int k = 0; k < 4; ++k) gather8(L, baseA[k], vA[k]);
        }

        // Phase 5: consume quad 2p+1 (per-lane guard; only quad 15 can be OOB).
        if (jB < QP) interp_store(out, jB, vB, rdB, gdB, bdB);

        // Rotate inputs for next pair.
        RB = RB2; GB = GB2; BB = BB2;
    }
}

// Fallback if workspace is too small: direct fp32 gathers from global LUT.
__global__ __launch_bounds__(256) void lut3d_direct(const float* __restrict__ x,
                                                    const float* __restrict__ lut,
                                                    float* __restrict__ out) {
    const int img = blockIdx.y;
    const int i = (blockIdx.x * 256 + threadIdx.x) * 4;
    const float* xp = x + (size_t)img * 3 * HW + i;
    f32x4 Rv = *(const f32x4*)xp;
    f32x4 Gv = *(const f32x4*)(xp + HW);
    f32x4 Bv = *(const f32x4*)(xp + 2 * HW);
    float o0[4], o1[4], o2[4];
    const float inv = 32.0f / 1.000001f;
#pragma unroll
    for (int k = 0; k < 4; ++k) {
        float xr = Rv[k] * inv;
        float xg = Gv[k] * inv;
        float xb = Bv[k] * inv;
        int ri = (int)xr; ri = ri < 0 ? 0 : (ri > DIM - 2 ? DIM - 2 : ri);
        int gi = (int)xg; gi = gi < 0 ? 0 : (gi > DIM - 2 ? DIM - 2 : gi);
        int bi = (int)xb; bi = bi < 0 ? 0 : (bi > DIM - 2 ? DIM - 2 : bi);
        float rd = xr - (float)ri;
        float gd = xg - (float)gi;
        float bd = xb - (float)bi;
        int base = (bi * DIM + gi) * DIM + ri;
        float oc[3];
#pragma unroll
        for (int c = 0; c < 3; ++c) {
            const float* Lp = lut + c * NENT + base;
            float v000 = Lp[0],        v001 = Lp[1];
            float v010 = Lp[DIM],      v011 = Lp[DIM + 1];
            float v100 = Lp[D2],       v101 = Lp[D2 + 1];
            float v110 = Lp[D2 + DIM], v111 = Lp[D2 + DIM + 1];
            float q0 = lerpf(v000, v001, rd);
            float q1 = lerpf(v010, v011, rd);
            float q2 = lerpf(v100, v101, rd);
            float q3 = lerpf(v110, v111, rd);
            float p0 = lerpf(q0, q1, gd);
            float p1 = lerpf(q2, q3, gd);
            oc[c] = lerpf(p0, p1, bd);
        }
        o0[k] = oc[0]; o1[k] = oc[1]; o2[k] = oc[2];
    }
    float* op = out + (size_t)img * 3 * HW + i;
    f32x4 v0 = {o0[0], o0[1], o0[2], o0[3]};
    f32x4 v1 = {o1[0], o1[1], o1[2], o1[3]};
    f32x4 v2 = {o2[0], o2[1], o2[2], o2[3]};
    *(f32x4*)op = v0;
    *(f32x4*)(op + HW) = v1;
    *(f32x4*)(op + 2 * HW) = v2;
}

extern "C" void kernel_launch(void* const* d_in, const int* in_sizes, int n_in,
                              void* d_out, int out_size, void* d_ws, size_t ws_size,
                              hipStream_t stream) {
    const float* lut = (const float*)d_in[0];
    const float* x   = (const float*)d_in[1];
    float* out = (float*)d_out;

    if (ws_size >= (size_t)NENT * 4) {
        uint32_t* T = (uint32_t*)d_ws;
        build_packed10<<<(NENT + 255) / 256, 256, 0, stream>>>(lut, T);
        lut3d_lds<<<NBLK, BLK, 0, stream>>>(x, T, out);
    } else {
        const dim3 grid(HW / 4 / 256, NIMG);
        lut3d_direct<<<grid, dim3(256), 0, stream>>>(x, lut, out);
    }
}